// Round 6
// baseline (467.440 us; speedup 1.0000x reference)
//
#include <hip/hip_runtime.h>
#include <stdint.h>

typedef unsigned int u32;
typedef short short8 __attribute__((ext_vector_type(8)));
typedef short bf16x8 __attribute__((ext_vector_type(8)));
typedef float f32x4  __attribute__((ext_vector_type(4)));

#define B_ROWS 8192
#define HID    1024
#define KDIM   3072
#define NGATE  5

// GEMM tile: 256 batch rows x (5 gates x 64 hidden) per block, 8 waves 2Mx4N,
// per-wave output 128x80 (8 M-frags x 5 N-frags; N-frag == gate index).
// Persistent: grid 256, each block does work items (mb, jb) and (mb+16, jb).
#define BM 256
#define BN 320
#define BK 64
#define NT (KDIM / BK)     // 48 K-tiles per work item
#define NTT (2 * NT)       // 96 across both work items
#define LDSA_SH (BM * BK)            // 16384 shorts
#define LDSB_SH (BN * BK)            // 20480 shorts
#define BUF_SH  (LDSA_SH + LDSB_SH)  // 36864 shorts = 72 KiB
#define BUF_BYTES (BUF_SH * 2)       // 73728

// ---------- helpers ----------
__device__ __forceinline__ short f2bf(float f) {
  u32 u = __builtin_bit_cast(u32, f);
  u += 0x7FFFu + ((u >> 16) & 1u);   // round-to-nearest-even
  return (short)(u >> 16);
}

__device__ __forceinline__ float sigf(float v) { return 1.0f / (1.0f + __expf(-v)); }

__device__ __forceinline__ void async_copy16(const void* g, void* l) {
  __builtin_amdgcn_global_load_lds(
      (__attribute__((address_space(1))) void*)(g),
      (__attribute__((address_space(3))) void*)(l),
      16, 0, 0);
}

// ---------- conversion kernels ----------
__global__ void convert_combined(const float* __restrict__ x,
                                 const float* __restrict__ hl,
                                 const float* __restrict__ hr,
                                 short* __restrict__ out) {
  const int total  = B_ROWS * (KDIM / 8);
  const int stride = gridDim.x * blockDim.x;
  for (int i = blockIdx.x * blockDim.x + threadIdx.x; i < total; i += stride) {
    int row = i / (KDIM / 8);
    int col = (i - row * (KDIM / 8)) * 8;
    const float* src;
    if (col < 1024)      src = x  + (int64_t)row * 1024 + col;
    else if (col < 2048) src = hl + (int64_t)row * 1024 + (col - 1024);
    else                 src = hr + (int64_t)row * 1024 + (col - 2048);
    float4 v0 = ((const float4*)src)[0];
    float4 v1 = ((const float4*)src)[1];
    short8 r;
    r[0] = f2bf(v0.x); r[1] = f2bf(v0.y); r[2] = f2bf(v0.z); r[3] = f2bf(v0.w);
    r[4] = f2bf(v1.x); r[5] = f2bf(v1.y); r[6] = f2bf(v1.z); r[7] = f2bf(v1.w);
    *(short8*)(out + (int64_t)row * KDIM + col) = r;
  }
}

__global__ void convert_w(const float* __restrict__ Wf, short* __restrict__ out) {
  const int total  = NGATE * HID * (KDIM / 8);
  const int stride = gridDim.x * blockDim.x;
  for (int i = blockIdx.x * blockDim.x + threadIdx.x; i < total; i += stride) {
    int64_t e = (int64_t)i * 8;
    float4 v0 = ((const float4*)(Wf + e))[0];
    float4 v1 = ((const float4*)(Wf + e))[1];
    short8 r;
    r[0] = f2bf(v0.x); r[1] = f2bf(v0.y); r[2] = f2bf(v0.z); r[3] = f2bf(v0.w);
    r[4] = f2bf(v1.x); r[5] = f2bf(v1.y); r[6] = f2bf(v1.z); r[7] = f2bf(v1.w);
    *(short8*)(out + e) = r;
  }
}

// ---------- fused GEMM + LSTM-cell epilogue (m201-style 4-phase schedule) ----
// Per phase: {ds_read this phase's frags; issue staging rounds for tile t+2
// into slices of buf[t&1] that died last phase; barrier; lgkmcnt(0); setprio(1)
// 20xMFMA setprio(0); barrier}. B(t) dies after p0 (read once into bfr);
// A slice s dies after phase s; wave w's 4 A-rounds all lie in slice (w&3),
// staged at phase (w&3)+1 (wrapping to next tile's p0 for w&3==3).
// Tile-end wait: vmcnt(9) (w&3==3: vmcnt(5)) -- counted, never drains to 0
// until the tail; every load gets >= 7 phases of flight time.
__global__ __launch_bounds__(512, 2) void lstm_gemm(
    const short* __restrict__ Abf,   // [8192][3072] bf16
    const short* __restrict__ Wbf,   // [5120][3072] bf16
    const float* __restrict__ bias,  // [5120]
    const float* __restrict__ c_left,
    const float* __restrict__ c_right,
    float* __restrict__ out) {       // h at 0, c at 8192*1024
  __shared__ short lds[2 * BUF_SH];  // 144 KiB
  char* const ldsc = (char*)lds;

  const int tid = threadIdx.x;
  const int w  = tid >> 6;     // 0..7
  const int l  = tid & 63;
  const int wm = w >> 2;       // 0..1
  const int wn = w & 3;        // 0..3
  const int wsel = w & 3;      // A-slice this wave stages
  const int lc = l & 15;
  const int khalf = l >> 4;    // 0..3

  // XCD-aware bijective swizzle (256 % 8 == 0)
  const int bid = blockIdx.x;
  const int wg  = (bid & 7) * 32 + (bid >> 3);
  const int mb  = wg >> 4;     // 0..15
  const int jb  = wg & 15;     // 0..15
  const int j0  = jb * 64;
  const u32 aBase0 = (u32)(mb * BM) * KDIM;            // work 0
  const u32 aBase1 = aBase0 + (u32)(16 * BM) * KDIM;   // work 1

  // staging lane constants: per wave-load 8 rows x 128B; lane -> row l>>3,
  // 16B slot (l&7) XOR row (pre-swizzled source, rule #21)
  const int r8 = l >> 3;
  const int sl = (l & 7) ^ r8;
  u32 laneA[4], laneB[5];
#pragma unroll
  for (int i = 0; i < 4; ++i)
    laneA[i] = (u32)((w * 4 + i) * 8 + r8) * KDIM + sl * 8;
#pragma unroll
  for (int i = 0; i < 5; ++i) {
    int rb = (w * 5 + i) * 8 + r8;                 // 0..319
    int g  = (rb % 80) >> 4;
    int dj = (rb / 80) * 16 + (rb & 15);
    laneB[i] = (u32)(g * HID + j0 + dj) * KDIM + sl * 8;
  }

  // staging helpers: s = global tile index 0..95
  auto stageA = [&](int s) {
    const u32 off = (s >= NT ? aBase1 + (u32)(s - NT) * BK : aBase0 + (u32)s * BK);
    short* dst = lds + (s & 1) * BUF_SH + w * 2048;
#pragma unroll
    for (int i = 0; i < 4; ++i)
      async_copy16(Abf + laneA[i] + off, dst + i * 512);
  };
  auto stageB = [&](int s) {
    const u32 off = (u32)(s >= NT ? s - NT : s) * BK;
    short* dst = lds + (s & 1) * BUF_SH + LDSA_SH + w * 2560;
#pragma unroll
    for (int i = 0; i < 5; ++i)
      async_copy16(Wbf + laneB[i] + off, dst + i * 512);
  };

  // ds_read byte addresses (buffer 0); row&7 == lc&7 since rows are 16k+lc
  const u32 sw0 = (u32)(((khalf    ) ^ (lc & 7)) * 16);
  const u32 sw1 = (u32)(((khalf + 4) ^ (lc & 7)) * 16);
  u32 aAd0 = (u32)((wm * 128 + lc) * 128) + sw0;
  u32 aAd1 = (u32)((wm * 128 + lc) * 128) + sw1;
  u32 bAd0 = (u32)(LDSA_SH * 2) + (u32)((wn * 80 + lc) * 128) + sw0;
  u32 bAd1 = (u32)(LDSA_SH * 2) + (u32)((wn * 80 + lc) * 128) + sw1;

  f32x4 acc[8][5];
  const f32x4 zero = {0.0f, 0.0f, 0.0f, 0.0f};
#pragma unroll
  for (int m = 0; m < 8; ++m)
#pragma unroll
    for (int n = 0; n < 5; ++n) acc[m][n] = zero;

  // epilogue writer (runs once per work item)
  const int j = j0 + wn * 16 + lc;
  auto epilogue = [&](int m0) {
    float bi[5];
#pragma unroll
    for (int g = 0; g < 5; ++g) bi[g] = bias[g * HID + j];
#pragma unroll
    for (int m = 0; m < 8; ++m) {
#pragma unroll
      for (int r = 0; r < 4; ++r) {
        const int row = m0 + wm * 128 + m * 16 + khalf * 4 + r;
        const int off = row * HID + j;
        float iv  = sigf(acc[m][0][r] + bi[0]);
        float flv = sigf(acc[m][1][r] + bi[1]);
        float frv = sigf(acc[m][2][r] + bi[2]);
        float ov  = sigf(acc[m][3][r] + bi[3]);
        float uv  = tanhf(acc[m][4][r] + bi[4]);
        float cv  = iv * uv + flv * c_left[off] + frv * c_right[off];
        out[off] = ov * tanhf(cv);
        out[B_ROWS * HID + off] = cv;
      }
    }
  };

  // ---- prologue: stage tiles 0 and 1 fully; wait only for tile 0 ----
  stageA(0); stageB(0);
  stageA(1); stageB(1);
  asm volatile("s_waitcnt vmcnt(9)" ::: "memory");
  __builtin_amdgcn_s_barrier();

  int bufd = BUF_BYTES;
  for (int T = 0; T < NTT; ++T) {
    bf16x8 bfr[5][2];
#pragma unroll
    for (int p = 0; p < 4; ++p) {
      // ---- read-step: this phase's fragments ----
      if (p == 0) {
#pragma unroll
        for (int nf = 0; nf < 5; ++nf) {
          bfr[nf][0] = *(const bf16x8*)(ldsc + bAd0 + nf * 2048);
          bfr[nf][1] = *(const bf16x8*)(ldsc + bAd1 + nf * 2048);
        }
      }
      bf16x8 af[2][2];
#pragma unroll
      for (int mf = 0; mf < 2; ++mf) {
        af[mf][0] = *(const bf16x8*)(ldsc + aAd0 + (p * 32 + mf * 16) * 128);
        af[mf][1] = *(const bf16x8*)(ldsc + aAd1 + (p * 32 + mf * 16) * 128);
      }
      // ---- staging issues (into slices that died last phase) ----
      if (p == 0) {
        if (wsel == 3 && T >= 1 && T + 1 < NTT) stageA(T + 1);
      } else if (p == 1) {
        if (T + 2 < NTT) { stageB(T + 2); if (wsel == 0) stageA(T + 2); }
      } else if (p == 2) {
        if (wsel == 1 && T + 2 < NTT) stageA(T + 2);
      } else {
        if (wsel == 2 && T + 2 < NTT) stageA(T + 2);
      }
      __builtin_amdgcn_sched_barrier(0);
      __builtin_amdgcn_s_barrier();
      asm volatile("s_waitcnt lgkmcnt(0)" ::: "memory");
      __builtin_amdgcn_sched_barrier(0);
      __builtin_amdgcn_s_setprio(1);
#pragma unroll
      for (int mf = 0; mf < 2; ++mf)
#pragma unroll
        for (int nf = 0; nf < 5; ++nf)
#pragma unroll
          for (int kk = 0; kk < 2; ++kk)
            acc[p * 2 + mf][nf] = __builtin_amdgcn_mfma_f32_16x16x32_bf16(
                af[mf][kk], bfr[nf][kk], acc[p * 2 + mf][nf], 0, 0, 0);
      __builtin_amdgcn_s_setprio(0);
      __builtin_amdgcn_sched_barrier(0);
      if (p == 3) {
        // counted tile-end wait: forces tile T+1 landed, keeps T+2 in flight
        if (T < NTT - 2) {
          if (wsel == 3) asm volatile("s_waitcnt vmcnt(5)" ::: "memory");
          else           asm volatile("s_waitcnt vmcnt(9)" ::: "memory");
        } else if (T == NTT - 2) {
          asm volatile("s_waitcnt vmcnt(0)" ::: "memory");
        }
      }
      __builtin_amdgcn_s_barrier();
    }
    aAd0 += bufd; aAd1 += bufd; bAd0 += bufd; bAd1 += bufd;
    bufd = -bufd;

    if (T == NT - 1) {   // work-0 done: epilogue overlaps in-flight staging
      epilogue(mb * BM);
#pragma unroll
      for (int m = 0; m < 8; ++m)
#pragma unroll
        for (int n = 0; n < 5; ++n) acc[m][n] = zero;
    }
  }
  epilogue(mb * BM + 16 * BM);
}

// ---------- fp32 fallback (only if ws too small) ----------
__global__ void lstm_fallback(const float* __restrict__ x, const float* __restrict__ hl,
                              const float* __restrict__ hr, const float* __restrict__ cl,
                              const float* __restrict__ cr, const float* __restrict__ W,
                              const float* __restrict__ b, float* __restrict__ out) {
  int64_t idx = (int64_t)blockIdx.x * blockDim.x + threadIdx.x;
  if (idx >= (int64_t)B_ROWS * HID) return;
  int bi = (int)(idx >> 10);
  int j  = (int)(idx & 1023);
  float acc[5];
#pragma unroll
  for (int g = 0; g < 5; ++g) acc[g] = b[g * HID + j];
  const float* segs[3] = {x + (int64_t)bi * 1024, hl + (int64_t)bi * 1024,
                          hr + (int64_t)bi * 1024};
  for (int s = 0; s < 3; ++s) {
    const float4* v = (const float4*)segs[s];
    for (int k4 = 0; k4 < 256; ++k4) {
      float4 a = v[k4];
#pragma unroll
      for (int g = 0; g < 5; ++g) {
        const float4 wv = *(const float4*)(W + (int64_t)(g * HID + j) * KDIM + s * 1024 + k4 * 4);
        acc[g] += a.x * wv.x + a.y * wv.y + a.z * wv.z + a.w * wv.w;
      }
    }
  }
  float iv = sigf(acc[0]), fl = sigf(acc[1]), fr = sigf(acc[2]), ov = sigf(acc[3]);
  float uv = tanhf(acc[4]);
  float cv = iv * uv + fl * cl[idx] + fr * cr[idx];
  out[idx] = ov * tanhf(cv);
  out[(int64_t)B_ROWS * HID + idx] = cv;
}

// ---------- host ----------
extern "C" void kernel_launch(void* const* d_in, const int* in_sizes, int n_in,
                              void* d_out, int out_size, void* d_ws, size_t ws_size,
                              hipStream_t stream) {
  const float* x  = (const float*)d_in[0];
  const float* hl = (const float*)d_in[1];
  const float* cl = (const float*)d_in[2];
  const float* hr = (const float*)d_in[3];
  const float* cr = (const float*)d_in[4];
  const float* W  = (const float*)d_in[5];
  const float* b  = (const float*)d_in[6];
  float* out = (float*)d_out;

  const size_t needA = (size_t)B_ROWS * KDIM * sizeof(short);      // 48 MiB
  const size_t needW = (size_t)NGATE * HID * KDIM * sizeof(short); // 30 MiB

  if (ws_size >= needA + needW) {
    short* Abf = (short*)d_ws;
    short* Wbf = (short*)((char*)d_ws + needA);
    convert_combined<<<2048, 256, 0, stream>>>(x, hl, hr, Abf);
    convert_w<<<2048, 256, 0, stream>>>(W, Wbf);
    lstm_gemm<<<256, 512, 0, stream>>>(Abf, Wbf, b, cl, cr, out);
  } else {
    lstm_fallback<<<(B_ROWS * HID) / 256, 256, 0, stream>>>(x, hl, hr, cl, cr, W, b, out);
  }
}